// Round 7
// baseline (202.506 us; speedup 1.0000x reference)
//
#include <hip/hip_runtime.h>
#include <hip/hip_bf16.h>
#include <math.h>

#define B_ 4
#define CIN 64
#define H_ 160
#define W_ 160
#define COUT 64
#define KK_ 9
#define HW_ (H_ * W_)
#define KTOT 576      // 9 taps * 64 channels
#define CPITCH 200    // chunk LDS pitch (u16): 400 B, 100 dwords == 4 mod 32 banks
#define XPITCH 72     // strip pitch (u16): 144 B = 9*16, b128-aligned, bank-rotating
#define SLPITCH 17    // offset-logit LDS pitch (floats)
#define NTILE 6400    // (B*HW)/16
#define TPX   800     // tiles per XCD slice (NTILE/8)

typedef __attribute__((ext_vector_type(8))) short bf16x8;
typedef __attribute__((ext_vector_type(4))) float f32x4;

__device__ inline unsigned short f2bf(float f) {
    unsigned int u = __float_as_uint(f);
    u = (u + 0x7FFF + ((u >> 16) & 1)) >> 16;   // round-to-nearest-even
    return (unsigned short)u;
}

// HW bf16 convert (RNE, bit-identical to f2bf on finite inputs), 1 VALU op
__device__ inline unsigned short bfc(float f) {
    __hip_bfloat16 h = __float2bfloat16(f);
    union { __hip_bfloat16 h; unsigned short u; } cv;
    cv.h = h;
    return cv.u;
}

// ---------------------------------------------------------------------------
// Kernel 1 (merged prep): grid-split into
//   [0, 1600)        : transpose x (NCHW fp32) -> xt NHWC fp32
//   [1600, 1744)     : main weight -> wB bf16 [o][tap*64+c]
//   [1744, 1816)     : offset weight -> wB2 bf16 [n(32,pad0)][tap*64+c]
// ---------------------------------------------------------------------------
__global__ __launch_bounds__(256) void prep_all_k(const float* __restrict__ x,
                                                  const float* __restrict__ wgt,
                                                  const float* __restrict__ ow,
                                                  float* __restrict__ xt,
                                                  unsigned short* __restrict__ wB,
                                                  unsigned short* __restrict__ wB2) {
    __shared__ float tile[64][65];
    int bid = blockIdx.x;
    int t = threadIdx.x;

    if (bid < 1600) {
        int pbk = bid % 400, b = bid / 400;    // 400 pixel-blocks of 64 per image
        int p0 = pbk * 64;
        const float* xp = x + (size_t)b * CIN * HW_ + p0;

        int pg = (t & 15) * 4, cr = t >> 4;
#pragma unroll
        for (int i = 0; i < 4; i++) {
            int c = i * 16 + cr;
            float4 v = *(const float4*)(xp + (size_t)c * HW_ + pg);
            tile[c][pg]     = v.x;
            tile[c][pg + 1] = v.y;
            tile[c][pg + 2] = v.z;
            tile[c][pg + 3] = v.w;
        }
        __syncthreads();

        int c4 = (t & 15) * 4, pr = t >> 4;
        float* op = xt + ((size_t)b * HW_ + p0) * 64 + c4;
#pragma unroll
        for (int i = 0; i < 4; i++) {
            int p = i * 16 + pr;
            float4 v;
            v.x = tile[c4][p];
            v.y = tile[c4 + 1][p];
            v.z = tile[c4 + 2][p];
            v.w = tile[c4 + 3][p];
            *(float4*)(op + (size_t)p * 64) = v;
        }
    } else if (bid < 1744) {
        int i = (bid - 1600) * 256 + t;          // 64*576 = 36864
        int o = i / KTOT, r = i % KTOT;
        int tap = r >> 6, c = r & 63;
        wB[i] = f2bf(wgt[(o * CIN + c) * KK_ + tap]);
    } else {
        int i = (bid - 1744) * 256 + t;          // 32*576 = 18432
        int n = i / KTOT, r = i % KTOT;
        int tap = r >> 6, c = r & 63;
        wB2[i] = (n < 27) ? f2bf(ow[(n * CIN + c) * KK_ + tap]) : (unsigned short)0;
    }
}

// ---------------------------------------------------------------------------
// Kernel 2: FUSED DCNv2 per 16-pixel tile, K-CHUNKED, D PIPELINED.
//  A: 54-row strip -> sX bf16 (7.8 KB)
//  B: offset GEMM (waves 0,1) -> slog (verified)
//  C': bilinear params, per-wave task subset (verified)
//  D/E: 6 gather batches (24 loads each) pipelined 1 deep; intra-chunk
//       barriers are lgkmcnt(0)+s_barrier (NO vmcnt drain) so the prefetched
//       batch stays in flight across E_c's MFMA.  Task map identical to R6:
//       task = 24*bi + 4*j + wv,  chunk c = bi>>1, local tap = tap-3c.
//  LDS ~14.3 KB -> 8 blocks/CU cap (R6-verified).
// ---------------------------------------------------------------------------
__global__ __launch_bounds__(256, 8) void fused_dcn_k(const float* __restrict__ xt,
                                                      const unsigned short* __restrict__ wB2,
                                                      const float* __restrict__ ob,
                                                      const unsigned short* __restrict__ wB,
                                                      const float* __restrict__ bias,
                                                      float* __restrict__ out) {
    __shared__ __align__(16) char ubuf[7776];              // sX (A/B) -> sAc (D/E)
    __shared__ __align__(16) char pbuf[144 * 32];          // spar_w | spar_o, 4.6 KB
    __shared__ float slog[27 * SLPITCH];                   // 1.8 KB
    unsigned short* sX  = (unsigned short*)ubuf;           // 54 x XPITCH
    unsigned short* sAc = (unsigned short*)ubuf;           // 16 x CPITCH (chunk)
    float4* spar_w = (float4*)pbuf;
    int4*   spar_o = (int4*)(pbuf + 144 * 16);

    int t = threadIdx.x;
    int lane = t & 63, wv = t >> 6;
    int bid = blockIdx.x;
    int tile = (bid & 7) * TPX + (bid >> 3);   // XCD-contiguous image slices
    int gp0 = tile * 16;                // 16 | W: one row, one b per block
    int wo0 = gp0 % W_;
    int tmp = gp0 / W_;
    int ho = tmp % H_;
    int b  = tmp / H_;

    const float* xb = xt + (size_t)b * HW_ * 64 + lane;

    // ---- phase A: 54-row strip load (zero-pad OOB), lanes = 64 channels ----
    for (int i = 0; i < 14; i++) {
        int r = i * 4 + wv;             // 0..55
        if (r < 54) {
            int yy = ho - 1 + r / 18;
            int xx = wo0 - 1 + r % 18;
            float v = 0.f;
            if (yy >= 0 && yy < H_ && xx >= 0 && xx < W_)
                v = xb[(size_t)(yy * W_ + xx) * 64];
            sX[r * XPITCH + lane] = bfc(v);
        }
    }
    __syncthreads();

    // ---- phase B: offset GEMM (waves 0,1), A-frag from sX, D -> slog ----
    if (wv < 2) {
        int m = lane & 15, q = lane >> 4;
        int oc = wv * 16 + m;
        float bv = (oc < 27) ? ob[oc] : 0.f;
        f32x4 acc  = {bv, bv, bv, bv};
        f32x4 acc2 = {0.f, 0.f, 0.f, 0.f};
        const unsigned short* brow = wB2 + oc * KTOT + q * 8;
#pragma unroll
        for (int tap = 0; tap < 9; tap++) {
            int row = (tap / 3) * 18 + (tap % 3) + m;       // strip row for (m, tap)
            const unsigned short* sxr = sX + row * XPITCH + q * 8;
            bf16x8 af0 = *(const bf16x8*)(sxr);
            bf16x8 af1 = *(const bf16x8*)(sxr + 32);
            bf16x8 b0  = *(const bf16x8*)(brow + (2 * tap) * 32);
            bf16x8 b1  = *(const bf16x8*)(brow + (2 * tap + 1) * 32);
            acc  = __builtin_amdgcn_mfma_f32_16x16x32_bf16(af0, b0, acc,  0, 0, 0);
            acc2 = __builtin_amdgcn_mfma_f32_16x16x32_bf16(af1, b1, acc2, 0, 0, 0);
        }
#pragma unroll
        for (int r = 0; r < 4; r++) acc[r] += acc2[r];
        if (oc < 27) {
            float* sl = slog + oc * SLPITCH + q * 4;        // pixel = q*4 + reg
            if (oc < 18) {
#pragma unroll
                for (int r = 0; r < 4; r++) sl[r] = acc[r];
            } else {
#pragma unroll
                for (int r = 0; r < 4; r++) sl[r] = 1.f / (1.f + expf(-acc[r]));
            }
        }
    }
    __syncthreads();

    // ---- phase C': bilinear params, per-wave task subset {4L+wv} ----
    if (lane < 36) {
        int task = lane * 4 + wv;
        int p = task & 15, k = task >> 4;
        float dyv = slog[(2 * k) * SLPITCH + p];
        float dxv = slog[(2 * k + 1) * SLPITCH + p];
        float mv  = slog[(18 + k) * SLPITCH + p];
        float py = dyv + (float)(k / 3) + (float)(ho - 1);
        float px = dxv + (float)(k % 3) + (float)(wo0 + p - 1);
        float y0f = floorf(py), x0f = floorf(px);
        float wy1 = py - y0f, wx1 = px - x0f;
        float wy0 = 1.f - wy1, wx0 = 1.f - wx1;
        int y0 = (int)y0f, x0 = (int)x0f;
        bool yv0 = (y0 >= 0) && (y0 < H_);
        bool yv1 = (y0 + 1 >= 0) && (y0 + 1 < H_);
        bool xv0 = (x0 >= 0) && (x0 < W_);
        bool xv1 = (x0 + 1 >= 0) && (x0 + 1 < W_);
        float4 w4;
        w4.x = (yv0 && xv0) ? wy0 * wx0 * mv : 0.f;
        w4.y = (yv0 && xv1) ? wy0 * wx1 * mv : 0.f;
        w4.z = (yv1 && xv0) ? wy1 * wx0 * mv : 0.f;
        w4.w = (yv1 && xv1) ? wy1 * wx1 * mv : 0.f;
        spar_w[task] = w4;
        int yc0 = min(max(y0, 0), H_ - 1), yc1 = min(max(y0 + 1, 0), H_ - 1);
        int xc0 = min(max(x0, 0), W_ - 1), xc1 = min(max(x0 + 1, 0), W_ - 1);
        int4 o4;                                   // BYTE offsets (elem*64*4)
        o4.x = (yc0 * W_ + xc0) * 256;
        o4.y = (yc0 * W_ + xc1) * 256;
        o4.z = (yc1 * W_ + xc0) * 256;
        o4.w = (yc1 * W_ + xc1) * 256;
        spar_o[task] = o4;
    }
    // within-wave C'->D dependency: drain LDS writes, no block barrier needed
    __asm__ volatile("s_waitcnt lgkmcnt(0)" ::: "memory");

    // ---- persistent accumulators for main GEMM ----
    int m = lane & 15, q = lane >> 4;
    int o0 = wv * 16 + m;
    float b0v = bias[o0];
    f32x4 acc0 = {b0v, b0v, b0v, b0v};
    f32x4 acc1 = {0.f, 0.f, 0.f, 0.f};
    const unsigned short* br0 = wB + o0 * KTOT + q * 8;
    const unsigned short* arow = sAc + m * CPITCH + q * 8;

    unsigned lane4 = (unsigned)lane << 2;
    const char* xu = (const char*)xt + (size_t)b * ((size_t)HW_ * 64 * 4);

    // ---- D/E pipelined: 6 batches (24 loads each), 1-deep prefetch ----
    float v00[6], v01[6], v10[6], v11[6];
    // prologue: issue batch 0 (tasks 0..23 of this wave)
#pragma unroll
    for (int j = 0; j < 6; j++) {
        int task = j * 4 + wv;
        int4 o4 = spar_o[task];
        v00[j] = *(const float*)(xu + ((unsigned)o4.x + lane4));
        v01[j] = *(const float*)(xu + ((unsigned)o4.y + lane4));
        v10[j] = *(const float*)(xu + ((unsigned)o4.z + lane4));
        v11[j] = *(const float*)(xu + ((unsigned)o4.w + lane4));
    }

#pragma unroll
    for (int c = 0; c < 3; c++) {
#pragma unroll
        for (int g = 0; g < 2; g++) {
            int bi = c * 2 + g;
            // consume current batch (compiler inserts vmcnt wait here)
            float vres[6];
#pragma unroll
            for (int j = 0; j < 6; j++) {
                int task = bi * 24 + j * 4 + wv;
                float4 w4 = spar_w[task];
                vres[j] = v00[j] * w4.x + v01[j] * w4.y
                        + v10[j] * w4.z + v11[j] * w4.w;
            }
            // issue next batch; stays in flight across barrier + E_c
            if (bi < 5) {
#pragma unroll
                for (int j = 0; j < 6; j++) {
                    int task = (bi + 1) * 24 + j * 4 + wv;
                    int4 o4 = spar_o[task];
                    v00[j] = *(const float*)(xu + ((unsigned)o4.x + lane4));
                    v01[j] = *(const float*)(xu + ((unsigned)o4.y + lane4));
                    v10[j] = *(const float*)(xu + ((unsigned)o4.z + lane4));
                    v11[j] = *(const float*)(xu + ((unsigned)o4.w + lane4));
                }
            }
            // write sAc rows for this batch
#pragma unroll
            for (int j = 0; j < 6; j++) {
                int task = bi * 24 + j * 4 + wv;
                int p = task & 15, kc = (task >> 4) - 3 * c;   // local tap 0..2
                sAc[p * CPITCH + kc * 64 + lane] = bfc(vres[j]);
            }
        }
        // LDS-only barrier: sAc writes visible, global loads stay in flight
        __asm__ volatile("s_waitcnt lgkmcnt(0)" ::: "memory");
        __builtin_amdgcn_s_barrier();

        // E_c: 6 MFMA (3 local taps x 2 K-slices), accumulate
#pragma unroll
        for (int tl = 0; tl < 3; tl++) {
            bf16x8 af0 = *(const bf16x8*)(arow + (2 * tl) * 32);
            bf16x8 af1 = *(const bf16x8*)(arow + (2 * tl + 1) * 32);
            bf16x8 b0  = *(const bf16x8*)(br0 + ((c * 3 + tl) * 2) * 32);
            bf16x8 b1  = *(const bf16x8*)(br0 + ((c * 3 + tl) * 2 + 1) * 32);
            acc0 = __builtin_amdgcn_mfma_f32_16x16x32_bf16(af0, b0, acc0, 0, 0, 0);
            acc1 = __builtin_amdgcn_mfma_f32_16x16x32_bf16(af1, b1, acc1, 0, 0, 0);
        }
        if (c < 2) {
            // LDS-only barrier: E_c reads done before next chunk overwrites
            __asm__ volatile("s_waitcnt lgkmcnt(0)" ::: "memory");
            __builtin_amdgcn_s_barrier();
        }
    }

#pragma unroll
    for (int r = 0; r < 4; r++) acc0[r] += acc1[r];

    // ---- direct store (verified): pixel = q*4 + reg ----
    size_t a0 = ((size_t)(b * COUT + o0)) * HW_ + (size_t)ho * W_ + wo0 + q * 4;
    float4 r0; r0.x = acc0[0]; r0.y = acc0[1]; r0.z = acc0[2]; r0.w = acc0[3];
    *(float4*)(out + a0) = r0;
}

// ---------------------------------------------------------------------------
extern "C" void kernel_launch(void* const* d_in, const int* in_sizes, int n_in,
                              void* d_out, int out_size, void* d_ws, size_t ws_size,
                              hipStream_t stream) {
    const float* x    = (const float*)d_in[0];   // (4,64,160,160)
    const float* ow   = (const float*)d_in[1];   // (27,64,3,3)
    const float* ob   = (const float*)d_in[2];   // (27,)
    const float* wgt  = (const float*)d_in[3];   // (64,64,3,3)
    const float* bias = (const float*)d_in[4];   // (64,)
    float* out = (float*)d_out;                  // (4,64,160,160) fp32

    // workspace: xt fp32 NHWC | wB bf16 | wB2 bf16   (~26.3 MB)
    float* ws  = (float*)d_ws;
    float* xt  = ws;                                            // 6,553,600 f32
    unsigned short* wB  = (unsigned short*)(xt + (size_t)B_ * HW_ * CIN);  // 36,864 u16
    unsigned short* wB2 = wB + (size_t)COUT * KTOT;                        // 18,432 u16

    prep_all_k<<<1816, 256, 0, stream>>>(x, wgt, ow, xt, wB, wB2);
    fused_dcn_k<<<NTILE, 256, 0, stream>>>(xt, wB2, ob, wB, bias, out);
}

// Round 10
// 182.826 us; speedup vs baseline: 1.1076x; 1.1076x over previous
//
#include <hip/hip_runtime.h>
#include <hip/hip_bf16.h>
#include <math.h>

#define B_ 4
#define CIN 64
#define H_ 160
#define W_ 160
#define COUT 64
#define KK_ 9
#define HW_ (H_ * W_)
#define KTOT 576      // 9 taps * 64 channels
#define CP32 200      // sAc pitch (u16): 400 B, 100 dw == 4 mod 32 banks
#define XPITCH 72     // strip pitch (u16): 144 B, bank-rotating
#define SL32 33       // slog pitch (floats): 33 dw == 1 mod 32, rotating
#define NT32 3200     // (B*HW)/32
#define TPX32 400     // tiles per XCD slice (NT32/8)

typedef __attribute__((ext_vector_type(8))) short bf16x8;
typedef __attribute__((ext_vector_type(4))) float f32x4;

__device__ inline unsigned short f2bf(float f) {
    unsigned int u = __float_as_uint(f);
    u = (u + 0x7FFF + ((u >> 16) & 1)) >> 16;   // round-to-nearest-even
    return (unsigned short)u;
}

// HW bf16 convert (RNE, bit-identical to f2bf on finite inputs), 1 VALU op
__device__ inline unsigned short bfc(float f) {
    __hip_bfloat16 h = __float2bfloat16(f);
    union { __hip_bfloat16 h; unsigned short u; } cv;
    cv.h = h;
    return cv.u;
}

// ---------------------------------------------------------------------------
// Kernel 1 (merged prep): unchanged (verified).
// ---------------------------------------------------------------------------
__global__ __launch_bounds__(256) void prep_all_k(const float* __restrict__ x,
                                                  const float* __restrict__ wgt,
                                                  const float* __restrict__ ow,
                                                  float* __restrict__ xt,
                                                  unsigned short* __restrict__ wB,
                                                  unsigned short* __restrict__ wB2) {
    __shared__ float tile[64][65];
    int bid = blockIdx.x;
    int t = threadIdx.x;

    if (bid < 1600) {
        int pbk = bid % 400, b = bid / 400;    // 400 pixel-blocks of 64 per image
        int p0 = pbk * 64;
        const float* xp = x + (size_t)b * CIN * HW_ + p0;

        int pg = (t & 15) * 4, cr = t >> 4;
#pragma unroll
        for (int i = 0; i < 4; i++) {
            int c = i * 16 + cr;
            float4 v = *(const float4*)(xp + (size_t)c * HW_ + pg);
            tile[c][pg]     = v.x;
            tile[c][pg + 1] = v.y;
            tile[c][pg + 2] = v.z;
            tile[c][pg + 3] = v.w;
        }
        __syncthreads();

        int c4 = (t & 15) * 4, pr = t >> 4;
        float* op = xt + ((size_t)b * HW_ + p0) * 64 + c4;
#pragma unroll
        for (int i = 0; i < 4; i++) {
            int p = i * 16 + pr;
            float4 v;
            v.x = tile[c4][p];
            v.y = tile[c4 + 1][p];
            v.z = tile[c4 + 2][p];
            v.w = tile[c4 + 3][p];
            *(float4*)(op + (size_t)p * 64) = v;
        }
    } else if (bid < 1744) {
        int i = (bid - 1600) * 256 + t;          // 64*576 = 36864
        int o = i / KTOT, r = i % KTOT;
        int tap = r >> 6, c = r & 63;
        wB[i] = f2bf(wgt[(o * CIN + c) * KK_ + tap]);
    } else {
        int i = (bid - 1744) * 256 + t;          // 32*576 = 18432
        int n = i / KTOT, r = i % KTOT;
        int tap = r >> 6, c = r & 63;
        wB2[i] = (n < 27) ? f2bf(ow[(n * CIN + c) * KK_ + tap]) : (unsigned short)0;
    }
}

// ---------------------------------------------------------------------------
// Kernel 2: FUSED DCNv2, 32 pixels per block (one row segment), K-chunked.
//  A : 3x34 strip (102 rows) -> sX bf16 (14.7 KB)
//  B : offset GEMM, ALL 4 waves: wave wv -> pixel-half h=wv>>1, oc-tile wv&1
//  C': bilinear params, per-wave tasks {l*4+wv}; 288 tasks, p=task&31,k=task>>5
//  chunks c=0..2: D_c gather (24 tasks/wave, 6-deep batches x4) -> sAc;
//                 E_c 12 MFMA/wave (3 taps x 2 K-slices x 2 pixel-halves,
//                 B-frags shared across halves), accumulate
//  LDS ~27.5 KB -> 5 blocks/CU (the measured TLP knee).
// ---------------------------------------------------------------------------
__global__ __launch_bounds__(256, 5) void fused_dcn_k(const float* __restrict__ xt,
                                                      const unsigned short* __restrict__ wB2,
                                                      const float* __restrict__ ob,
                                                      const unsigned short* __restrict__ wB,
                                                      const float* __restrict__ bias,
                                                      float* __restrict__ out) {
    __shared__ __align__(16) char ubuf[14688];             // sX (A/B) -> sAc (D/E)
    __shared__ __align__(16) char pbuf[288 * 32];          // spar_w | spar_o, 9.2 KB
    __shared__ float slog[27 * SL32];                      // 3.6 KB
    unsigned short* sX  = (unsigned short*)ubuf;           // 102 x XPITCH
    unsigned short* sAc = (unsigned short*)ubuf;           // 32 x CP32 (chunk)
    float4* spar_w = (float4*)pbuf;
    int4*   spar_o = (int4*)(pbuf + 288 * 16);

    int t = threadIdx.x;
    int lane = t & 63, wv = t >> 6;
    int bid = blockIdx.x;
    int tile = (bid & 7) * TPX32 + (bid >> 3); // XCD-contiguous image slices
    int gp0 = tile * 32;                // 32 | W: one row segment, one b
    int wo0 = gp0 % W_;
    int tmp = gp0 / W_;
    int ho = tmp % H_;
    int b  = tmp / H_;

    const float* xb = xt + (size_t)b * HW_ * 64 + lane;

    // ---- phase A: 102-row strip load (zero-pad OOB), lanes = channels ----
    for (int i = 0; i < 26; i++) {
        int r = i * 4 + wv;             // 0..103
        if (r < 102) {
            int yy = ho - 1 + r / 34;
            int xx = wo0 - 1 + r % 34;
            float v = 0.f;
            if (yy >= 0 && yy < H_ && xx >= 0 && xx < W_)
                v = xb[(size_t)(yy * W_ + xx) * 64];
            sX[r * XPITCH + lane] = bfc(v);
        }
    }
    __syncthreads();

    // ---- phase B: offset GEMM, all 4 waves (h = wv>>1, oc-tile wv&1) ----
    {
        int m = lane & 15, q = lane >> 4;
        int h  = wv >> 1;
        int ocl = (wv & 1) * 16 + m;
        float bv = (ocl < 27) ? ob[ocl] : 0.f;
        f32x4 acc  = {bv, bv, bv, bv};
        f32x4 acc2 = {0.f, 0.f, 0.f, 0.f};
        const unsigned short* brow = wB2 + ocl * KTOT + q * 8;
#pragma unroll
        for (int tap = 0; tap < 9; tap++) {
            int row = (tap / 3) * 34 + (tap % 3) + h * 16 + m;  // strip row
            const unsigned short* sxr = sX + row * XPITCH + q * 8;
            bf16x8 af0 = *(const bf16x8*)(sxr);
            bf16x8 af1 = *(const bf16x8*)(sxr + 32);
            bf16x8 b0  = *(const bf16x8*)(brow + (2 * tap) * 32);
            bf16x8 b1  = *(const bf16x8*)(brow + (2 * tap + 1) * 32);
            acc  = __builtin_amdgcn_mfma_f32_16x16x32_bf16(af0, b0, acc,  0, 0, 0);
            acc2 = __builtin_amdgcn_mfma_f32_16x16x32_bf16(af1, b1, acc2, 0, 0, 0);
        }
#pragma unroll
        for (int r = 0; r < 4; r++) acc[r] += acc2[r];
        if (ocl < 27) {
            float* sl = slog + ocl * SL32 + h * 16 + q * 4;     // pixel p32
            if (ocl < 18) {
#pragma unroll
                for (int r = 0; r < 4; r++) sl[r] = acc[r];
            } else {
#pragma unroll
                for (int r = 0; r < 4; r++) sl[r] = 1.f / (1.f + expf(-acc[r]));
            }
        }
    }
    __syncthreads();

    // ---- phase C': bilinear params, per-wave task subset {l*4+wv} ----
    for (int l = lane; l < 72; l += 64) {
        int task = l * 4 + wv;                 // < 288
        int p = task & 31, k = task >> 5;
        float dyv = slog[(2 * k) * SL32 + p];
        float dxv = slog[(2 * k + 1) * SL32 + p];
        float mv  = slog[(18 + k) * SL32 + p];
        float py = dyv + (float)(k / 3) + (float)(ho - 1);
        float px = dxv + (float)(k % 3) + (float)(wo0 + p - 1);
        float y0f = floorf(py), x0f = floorf(px);
        float wy1 = py - y0f, wx1 = px - x0f;
        float wy0 = 1.f - wy1, wx0 = 1.f - wx1;
        int y0 = (int)y0f, x0 = (int)x0f;
        bool yv0 = (y0 >= 0) && (y0 < H_);
        bool yv1 = (y0 + 1 >= 0) && (y0 + 1 < H_);
        bool xv0 = (x0 >= 0) && (x0 < W_);
        bool xv1 = (x0 + 1 >= 0) && (x0 + 1 < W_);
        float4 w4;
        w4.x = (yv0 && xv0) ? wy0 * wx0 * mv : 0.f;
        w4.y = (yv0 && xv1) ? wy0 * wx1 * mv : 0.f;
        w4.z = (yv1 && xv0) ? wy1 * wx0 * mv : 0.f;
        w4.w = (yv1 && xv1) ? wy1 * wx1 * mv : 0.f;
        spar_w[task] = w4;
        int yc0 = min(max(y0, 0), H_ - 1), yc1 = min(max(y0 + 1, 0), H_ - 1);
        int xc0 = min(max(x0, 0), W_ - 1), xc1 = min(max(x0 + 1, 0), W_ - 1);
        int4 o4;                               // BYTE offsets (elem*64*4)
        o4.x = (yc0 * W_ + xc0) * 256;
        o4.y = (yc0 * W_ + xc1) * 256;
        o4.z = (yc1 * W_ + xc0) * 256;
        o4.w = (yc1 * W_ + xc1) * 256;
        spar_o[task] = o4;
    }
    // within-wave C'->D dependency: drain LDS writes, no block barrier needed
    __asm__ volatile("s_waitcnt lgkmcnt(0)" ::: "memory");

    // ---- persistent accumulators for main GEMM (2 pixel-halves) ----
    int m = lane & 15, q = lane >> 4;
    int o0 = wv * 16 + m;
    float b0v = bias[o0];
    f32x4 acc00 = {b0v, b0v, b0v, b0v};        // h=0, even K-slice
    f32x4 acc01 = {0.f, 0.f, 0.f, 0.f};        // h=0, odd
    f32x4 acc10 = {b0v, b0v, b0v, b0v};        // h=1, even
    f32x4 acc11 = {0.f, 0.f, 0.f, 0.f};        // h=1, odd
    const unsigned short* br0 = wB + o0 * KTOT + q * 8;
    const unsigned short* arow0 = sAc + m * CP32 + q * 8;
    const unsigned short* arow1 = sAc + (16 + m) * CP32 + q * 8;

    unsigned lane4 = (unsigned)lane << 2;
    const char* xu = (const char*)xt + (size_t)b * ((size_t)HW_ * 64 * 4);

    // ---- chunks: D_c gather (3 taps, 96 tasks) -> sAc ; E_c 12-MFMA ----
#pragma unroll
    for (int c = 0; c < 3; c++) {
        // D_c: this wave's 24 tasks, four 6-task batches (R6-proven pattern)
#pragma unroll
        for (int g = 0; g < 4; g++) {
            float v00[6], v01[6], v10[6], v11[6];
#pragma unroll
            for (int j = 0; j < 6; j++) {
                int task = 96 * c + (g * 6 + j) * 4 + wv;
                int4 o4 = spar_o[task];
                v00[j] = *(const float*)(xu + ((unsigned)o4.x + lane4));
                v01[j] = *(const float*)(xu + ((unsigned)o4.y + lane4));
                v10[j] = *(const float*)(xu + ((unsigned)o4.z + lane4));
                v11[j] = *(const float*)(xu + ((unsigned)o4.w + lane4));
            }
#pragma unroll
            for (int j = 0; j < 6; j++) {
                int task = 96 * c + (g * 6 + j) * 4 + wv;
                float4 w4 = spar_w[task];
                int p = task & 31, kc = (task >> 5) - 3 * c;   // local tap 0..2
                float v = v00[j] * w4.x + v01[j] * w4.y
                        + v10[j] * w4.z + v11[j] * w4.w;
                sAc[p * CP32 + kc * 64 + lane] = bfc(v);
            }
        }
        __syncthreads();

        // E_c: 3 local taps x 2 K-slices x 2 halves; B-frags shared
#pragma unroll
        for (int tl = 0; tl < 3; tl++) {
            bf16x8 b0  = *(const bf16x8*)(br0 + ((c * 3 + tl) * 2) * 32);
            bf16x8 b1  = *(const bf16x8*)(br0 + ((c * 3 + tl) * 2 + 1) * 32);
            bf16x8 a00 = *(const bf16x8*)(arow0 + (2 * tl) * 32);
            bf16x8 a01 = *(const bf16x8*)(arow0 + (2 * tl + 1) * 32);
            bf16x8 a10 = *(const bf16x8*)(arow1 + (2 * tl) * 32);
            bf16x8 a11 = *(const bf16x8*)(arow1 + (2 * tl + 1) * 32);
            acc00 = __builtin_amdgcn_mfma_f32_16x16x32_bf16(a00, b0, acc00, 0, 0, 0);
            acc01 = __builtin_amdgcn_mfma_f32_16x16x32_bf16(a01, b1, acc01, 0, 0, 0);
            acc10 = __builtin_amdgcn_mfma_f32_16x16x32_bf16(a10, b0, acc10, 0, 0, 0);
            acc11 = __builtin_amdgcn_mfma_f32_16x16x32_bf16(a11, b1, acc11, 0, 0, 0);
        }
        if (c < 2) __syncthreads();    // E_c reads done before D_{c+1} overwrites
    }

#pragma unroll
    for (int r = 0; r < 4; r++) { acc00[r] += acc01[r]; acc10[r] += acc11[r]; }

    // ---- direct store: half 0 at wo0+q*4, half 1 at +16 ----
    size_t a0 = ((size_t)(b * COUT + o0)) * HW_ + (size_t)ho * W_ + wo0 + q * 4;
    float4 r0; r0.x = acc00[0]; r0.y = acc00[1]; r0.z = acc00[2]; r0.w = acc00[3];
    *(float4*)(out + a0) = r0;
    float4 r1; r1.x = acc10[0]; r1.y = acc10[1]; r1.z = acc10[2]; r1.w = acc10[3];
    *(float4*)(out + a0 + 16) = r1;
}

// ---------------------------------------------------------------------------
extern "C" void kernel_launch(void* const* d_in, const int* in_sizes, int n_in,
                              void* d_out, int out_size, void* d_ws, size_t ws_size,
                              hipStream_t stream) {
    const float* x    = (const float*)d_in[0];   // (4,64,160,160)
    const float* ow   = (const float*)d_in[1];   // (27,64,3,3)
    const float* ob   = (const float*)d_in[2];   // (27,)
    const float* wgt  = (const float*)d_in[3];   // (64,64,3,3)
    const float* bias = (const float*)d_in[4];   // (64,)
    float* out = (float*)d_out;                  // (4,64,160,160) fp32

    // workspace: xt fp32 NHWC | wB bf16 | wB2 bf16   (~26.3 MB)
    float* ws  = (float*)d_ws;
    float* xt  = ws;                                            // 6,553,600 f32
    unsigned short* wB  = (unsigned short*)(xt + (size_t)B_ * HW_ * CIN);  // 36,864 u16
    unsigned short* wB2 = wB + (size_t)COUT * KTOT;                        // 18,432 u16

    prep_all_k<<<1816, 256, 0, stream>>>(x, wgt, ow, xt, wB, wB2);
    fused_dcn_k<<<NT32, 256, 0, stream>>>(xt, wB2, ob, wB, bias, out);
}